// Round 3
// baseline (399.533 us; speedup 1.0000x reference)
//
#include <hip/hip_runtime.h>
#include <hip/hip_bf16.h>
#include <stdint.h>

#define B_ 16
#define S_ 2048
#define H_ 1024
#define N_ 128
#define K9 (9*H_)     // 9216: slots 0-7 = relation aggregates, slot 8 = Init (for w_f)
#define M_ (B_*N_)    // 2048

typedef __attribute__((ext_vector_type(8))) short s8vec;   // 8 x bf16 (4 VGPRs)
typedef __attribute__((ext_vector_type(4))) float f4vec;
typedef __hip_bfloat16 bf16;

// ---------------------------------------------------------------------------
// Kernel 0: per-batch sort by `numbers`, validity count, tie-group flags.
__global__ void k_sort(const int* __restrict__ num_ids, const int* __restrict__ is_resp,
                       const float* __restrict__ numbers,
                       int* __restrict__ sigma, int* __restrict__ newgrp,
                       int* __restrict__ respv, float* __restrict__ denom) {
    int b = blockIdx.x, i = threadIdx.x;
    __shared__ float nums[N_];
    __shared__ int sig[N_];
    __shared__ int cnt;
    float ni = numbers[b*N_ + i];
    int idv = num_ids[b*N_ + i];
    int valid = (idv >= 0) ? 1 : 0;
    nums[i] = ni;
    if (i == 0) cnt = 0;
    __syncthreads();
    int p = 0;
    for (int j = 0; j < N_; ++j) {
        float nj = nums[j];
        p += (nj < ni || (nj == ni && j < i)) ? 1 : 0;   // total order, ties by index
    }
    sig[p] = i;
    atomicAdd(&cnt, valid);
    __syncthreads();
    sigma[b*N_ + i] = sig[i];
    int cur = sig[i];
    int prv = (i > 0) ? sig[i-1] : 0;
    newgrp[b*N_ + i] = (i == 0 || nums[cur] != nums[prv]) ? 1 : 0;
    respv[b*N_ + i] = ((is_resp[b*N_ + i] == 1) ? 1 : 0) | (valid << 1);
    if (i == 0) denom[b] = fmaxf((float)(cnt - 1), 1.0f);
}

// ---------------------------------------------------------------------------
// Kernel 1: gather Init, alpha = sigmoid(Init.w_alpha), Init->A slot 8 (bf16),
// ascaled = valid * alpha / denom.
__global__ void k_gather(const float* __restrict__ word_emb, const int* __restrict__ num_ids,
                         const float* __restrict__ w_alpha, const float* __restrict__ b_alpha,
                         const float* __restrict__ denom,
                         bf16* __restrict__ A, float* __restrict__ ascaled) {
    int blk = blockIdx.x;
    int b = blk >> 7, n = blk & 127;
    int t = threadIdx.x;
    int idv = num_ids[b*N_ + n];
    int valid = (idv >= 0) ? 1 : 0;
    int idx = idv < 0 ? 0 : (idv > S_-1 ? S_-1 : idv);
    const float4* row = (const float4*)(word_emb + ((size_t)b*S_ + idx)*H_);
    float4 v = row[t];
    float4 w = ((const float4*)w_alpha)[t];
    float part = v.x*w.x + v.y*w.y + v.z*w.z + v.w*w.w;
    bf16* dst = A + (size_t)(b*N_ + n)*K9 + 8*H_ + t*4;
    dst[0] = __float2bfloat16(v.x);
    dst[1] = __float2bfloat16(v.y);
    dst[2] = __float2bfloat16(v.z);
    dst[3] = __float2bfloat16(v.w);
#pragma unroll
    for (int off = 32; off > 0; off >>= 1) part += __shfl_down(part, off, 64);
    __shared__ float red[4];
    if ((t & 63) == 0) red[t >> 6] = part;
    __syncthreads();
    if (t == 0) {
        float dot = red[0] + red[1] + red[2] + red[3] + b_alpha[0];
        float al = 1.0f / (1.0f + __expf(-dot));
        ascaled[b*N_ + n] = valid ? (al / denom[b]) : 0.0f;
    }
}

// ---------------------------------------------------------------------------
// Kernel 2a: W_r -> bf16 slots 0-7 (already [r][out][in] = B^T layout). 8192 blocks.
__global__ void k_wt(const float* __restrict__ W_r, bf16* __restrict__ Wt) {
    size_t o = ((size_t)blockIdx.x*256 + threadIdx.x)*4;
    float4 v = *(const float4*)(W_r + o);
    Wt[o+0] = __float2bfloat16(v.x);
    Wt[o+1] = __float2bfloat16(v.y);
    Wt[o+2] = __float2bfloat16(v.z);
    Wt[o+3] = __float2bfloat16(v.w);
}

// Kernel 2b: w_f [k][n] -> slot 8 as [n][k] via LDS 64x64 tile transpose.
__global__ void k_wf(const float* __restrict__ w_f, bf16* __restrict__ Wt8) {
    __shared__ float lds[64][65];
    int bi = blockIdx.x, bj = blockIdx.y;
    int t = threadIdx.x;
    int ty = t >> 4, tx = t & 15;
#pragma unroll
    for (int i = 0; i < 4; ++i) {
        int r = ty*4 + i;                                    // k index within tile
        float4 v = *(const float4*)(w_f + (size_t)(bi*64 + r)*H_ + bj*64 + tx*4);
        lds[r][tx*4+0] = v.x; lds[r][tx*4+1] = v.y;
        lds[r][tx*4+2] = v.z; lds[r][tx*4+3] = v.w;
    }
    __syncthreads();
#pragma unroll
    for (int i = 0; i < 4; ++i) {
        int n = ty*4 + i;                                    // out row within tile
        bf16* dst = Wt8 + (size_t)(bj*64 + n)*H_ + bi*64 + tx*4;
#pragma unroll
        for (int j = 0; j < 4; ++j)
            dst[j] = __float2bfloat16(lds[tx*4+j][n]);
    }
}

// ---------------------------------------------------------------------------
// Kernel 3: build A slots 0-7 via prefix sums over sorted order.
__global__ void k_build(const float* __restrict__ ascaled, const int* __restrict__ sigma,
                        const int* __restrict__ newgrp, const int* __restrict__ respv,
                        bf16* __restrict__ A) {
    int b = blockIdx.y;
    int h = blockIdx.x*64 + threadIdx.x;
    __shared__ float as_s[N_];
    __shared__ int sig_s[N_], ng_s[N_], rv_s[N_];
    for (int j = threadIdx.x; j < N_; j += 64) {
        as_s[j] = ascaled[b*N_ + j];
        sig_s[j] = sigma[b*N_ + j];
        ng_s[j] = newgrp[b*N_ + j];
        rv_s[j] = respv[b*N_ + j];
    }
    __syncthreads();
    const bf16* initcol = A + 8*H_ + h;
    float tot0 = 0.f, tot1 = 0.f;
    for (int i2 = 0; i2 < N_; ++i2) {
        float v = as_s[i2] * __bfloat162float(initcol[(size_t)(b*N_ + i2)*K9]);
        if (rv_s[i2] & 1) tot1 += v; else tot0 += v;
    }
    float cS0=0.f, cS1=0.f, cG0=0.f, cG1=0.f;   // strict prefix + current tie group
    for (int p = 0; p < N_; ++p) {
        int i2 = sig_s[p];
        if (ng_s[p]) { cS0 += cG0; cS1 += cG1; cG0 = 0.f; cG1 = 0.f; }
        float v = as_s[i2] * __bfloat162float(initcol[(size_t)(b*N_ + i2)*K9]);
        int resp = rv_s[i2] & 1;
        float vf = (rv_s[i2] >> 1) ? 1.0f : 0.0f;
        float G0 = cS0, G1 = cS1;                    // senders with num_j < num_i
        float L0 = tot0 - G0 - (resp ? 0.f : v);     // num_j >= num_i, j != i
        float L1 = tot1 - G1 - (resp ? v : 0.f);
        bf16* Ar = A + (size_t)(b*N_ + i2)*K9 + h;
        int rb = 2*resp, ob = 2*(1 - resp);
        Ar[(size_t)(rb+0)*H_]   = __float2bfloat16(L0*vf);
        Ar[(size_t)(rb+1)*H_]   = __float2bfloat16(L1*vf);
        Ar[(size_t)(4+rb+0)*H_] = __float2bfloat16(G0*vf);
        Ar[(size_t)(4+rb+1)*H_] = __float2bfloat16(G1*vf);
        bf16 z = __float2bfloat16(0.0f);
        Ar[(size_t)(ob+0)*H_]   = z;
        Ar[(size_t)(ob+1)*H_]   = z;
        Ar[(size_t)(4+ob+0)*H_] = z;
        Ar[(size_t)(4+ob+1)*H_] = z;
        if (resp) cG1 += v; else cG0 += v;
    }
}

// ---------------------------------------------------------------------------
// Kernel 4: split-K GEMM  out[2048,1024] += A[2048,9216] x Wt^T (atomicAdd f32).
// BM=128, BN=64, BK=32, KSPLIT=4 -> grid 16m x 16n x 4ks = 1024 blocks (4/CU),
// 256 threads = 2x2 waves, wave tile 64x32 (acc 4x2 of 16x16x32).
// LDS chunk layout [kchunk][row]: conflict-free (verified: 0 conflicts R2).
#define BM 128
#define BN 64
#define BK 32
#define KSPLIT 4
#define KSEG (K9/KSPLIT)   // 2304 = 72 * BK

__global__ __launch_bounds__(256) void k_gemm(const bf16* __restrict__ A,
                                              const bf16* __restrict__ Wt,
                                              float* __restrict__ out) {
    __shared__ __align__(16) bf16 As[BM*BK];   // 8 KB, chunk c -> [kq(=c>>7)][row(=c&127)]
    __shared__ __align__(16) bf16 Bs[BN*BK];   // 4 KB, chunk c -> [kq(=c>>6)][col(=c&63)]
    int tid = threadIdx.x;
    int w = tid >> 6, lane = tid & 63;
    int q = lane >> 4, r = lane & 15;
    int bid = blockIdx.x;
    int mtile = bid & 15, ntile = (bid >> 4) & 15, ks = bid >> 8;
    int rowBase = mtile * BM, colBase = ntile * BN;
    int wm = w >> 1, wn = w & 1;

    f4vec acc[4][2];
#pragma unroll
    for (int mt = 0; mt < 4; ++mt)
#pragma unroll
        for (int nt = 0; nt < 2; ++nt)
#pragma unroll
            for (int e = 0; e < 4; ++e) acc[mt][nt][e] = 0.0f;

    const size_t Abase = (size_t)rowBase * K9;
    const int kbeg = ks * KSEG, kend = kbeg + KSEG;
    for (int k0 = kbeg; k0 < kend; k0 += BK) {
        int slot = k0 >> 10, kin = k0 & 1023;
        // stage A: 512 chunks, 2/thread; chunk c: kq=c>>7, row=c&127; LDS off = c*16
        {
            int c = tid;
            const bf16* g = A + Abase + (size_t)(c & 127)*K9 + k0 + (c >> 7)*8;
            __builtin_amdgcn_global_load_lds((const __attribute__((address_space(1))) void*)g,
                (__attribute__((address_space(3))) void*)((char*)As + w*1024), 16, 0, 0);
            c = tid + 256;
            const bf16* g2 = A + Abase + (size_t)(c & 127)*K9 + k0 + (c >> 7)*8;
            __builtin_amdgcn_global_load_lds((const __attribute__((address_space(1))) void*)g2,
                (__attribute__((address_space(3))) void*)((char*)As + 4096 + w*1024), 16, 0, 0);
            // stage B: 256 chunks, 1/thread; chunk c: kq=c>>6, col=c&63
            c = tid;
            const bf16* gb = Wt + (size_t)slot*H_*H_ + (size_t)(colBase + (c & 63))*H_
                             + kin + (c >> 6)*8;
            __builtin_amdgcn_global_load_lds((const __attribute__((address_space(1))) void*)gb,
                (__attribute__((address_space(3))) void*)((char*)Bs + w*1024), 16, 0, 0);
        }
        __syncthreads();
        const short* Asp = (const short*)As;
        const short* Bsp = (const short*)Bs;
        s8vec af[4], bfr[2];
#pragma unroll
        for (int mt = 0; mt < 4; ++mt)
            af[mt] = *(const s8vec*)(Asp + ((size_t)q*128 + wm*64 + mt*16 + r)*8);
#pragma unroll
        for (int nt = 0; nt < 2; ++nt)
            bfr[nt] = *(const s8vec*)(Bsp + ((size_t)q*64 + wn*32 + nt*16 + r)*8);
#pragma unroll
        for (int mt = 0; mt < 4; ++mt)
#pragma unroll
            for (int nt = 0; nt < 2; ++nt)
                acc[mt][nt] = __builtin_amdgcn_mfma_f32_16x16x32_bf16(af[mt], bfr[nt],
                                                                      acc[mt][nt], 0, 0, 0);
        __syncthreads();
    }

#pragma unroll
    for (int mt = 0; mt < 4; ++mt)
#pragma unroll
        for (int nt = 0; nt < 2; ++nt)
#pragma unroll
            for (int e = 0; e < 4; ++e) {
                int rr = rowBase + wm*64 + mt*16 + q*4 + e;   // D row = quad*4+reg
                int cc = colBase + wn*32 + nt*16 + r;         // D col = lane&15
                atomicAdd(&out[(size_t)rr*H_ + cc], acc[mt][nt][e]);
            }
}

// ---------------------------------------------------------------------------
// Kernel 5: epilogue out = relu(out + b_f), in place. 2048 blocks x 256, float4.
__global__ void k_epi(float* __restrict__ out, const float* __restrict__ b_f) {
    size_t i4 = ((size_t)blockIdx.x*256 + threadIdx.x)*4;
    float4 v = *(float4*)(out + i4);
    int cc = (int)(i4 & 1023);
    float4 bv = *(const float4*)(b_f + cc);
    v.x = fmaxf(v.x + bv.x, 0.0f);
    v.y = fmaxf(v.y + bv.y, 0.0f);
    v.z = fmaxf(v.z + bv.z, 0.0f);
    v.w = fmaxf(v.w + bv.w, 0.0f);
    *(float4*)(out + i4) = v;
}

// ---------------------------------------------------------------------------
extern "C" void kernel_launch(void* const* d_in, const int* in_sizes, int n_in,
                              void* d_out, int out_size, void* d_ws, size_t ws_size,
                              hipStream_t stream) {
    (void)in_sizes; (void)n_in; (void)out_size; (void)ws_size;
    const float* word_emb = (const float*)d_in[0];
    const int*   num_ids  = (const int*)d_in[1];
    const int*   is_resp  = (const int*)d_in[2];
    const float* numbers  = (const float*)d_in[3];
    const float* w_alpha  = (const float*)d_in[4];
    const float* b_alpha  = (const float*)d_in[5];
    const float* w_f      = (const float*)d_in[6];
    const float* b_f      = (const float*)d_in[7];
    const float* W_r      = (const float*)d_in[8];
    float* out = (float*)d_out;

    char* ws = (char*)d_ws;
    bf16*  Aws     = (bf16*)(ws);                    // [2048][9216] bf16 = 37,748,736 B
    bf16*  Wt      = (bf16*)(ws + 37748736);         // [9][1024][1024] bf16 = 18,874,368 B
    float* ascaled = (float*)(ws + 56623104);
    int*   sigma   = (int*)(ws + 56631296);
    int*   newgrp  = (int*)(ws + 56639488);
    int*   respv   = (int*)(ws + 56647680);
    float* denom   = (float*)(ws + 56655872);

    hipMemsetAsync(out, 0, (size_t)M_*H_*sizeof(float), stream);
    k_sort  <<<16,   128, 0, stream>>>(num_ids, is_resp, numbers, sigma, newgrp, respv, denom);
    k_gather<<<2048, 256, 0, stream>>>(word_emb, num_ids, w_alpha, b_alpha, denom, Aws, ascaled);
    k_wt    <<<8192, 256, 0, stream>>>(W_r, Wt);
    k_wf    <<<dim3(16,16), 256, 0, stream>>>(w_f, Wt + (size_t)8*H_*H_);
    k_build <<<dim3(16,16), 64, 0, stream>>>(ascaled, sigma, newgrp, respv, Aws);
    k_gemm  <<<1024, 256, 0, stream>>>(Aws, Wt, out);
    k_epi   <<<2048, 256, 0, stream>>>(out, b_f);
}

// Round 4
// 369.906 us; speedup vs baseline: 1.0801x; 1.0801x over previous
//
#include <hip/hip_runtime.h>
#include <hip/hip_bf16.h>
#include <stdint.h>

#define B_ 16
#define S_ 2048
#define H_ 1024
#define N_ 128
#define M_ (B_*N_)    // 2048
#define K5 5120       // compact: 4 relation slots + Init slot (slot 4)
#define MP 2176       // padded rows: 17 tiles of 128 (class-0 block | class-1 block | pad)

typedef __attribute__((ext_vector_type(8))) short s8vec;   // 8 x bf16 (4 VGPRs)
typedef __attribute__((ext_vector_type(4))) float f4vec;
typedef __hip_bfloat16 bf16;

// ---------------------------------------------------------------------------
// Kernel 0: per-batch sort by `numbers`, validity count, tie-group flags.
__global__ void k_sort(const int* __restrict__ num_ids, const int* __restrict__ is_resp,
                       const float* __restrict__ numbers,
                       int* __restrict__ sigma, int* __restrict__ newgrp,
                       int* __restrict__ respv, float* __restrict__ denom) {
    int b = blockIdx.x, i = threadIdx.x;
    __shared__ float nums[N_];
    __shared__ int sig[N_];
    __shared__ int cnt;
    float ni = numbers[b*N_ + i];
    int idv = num_ids[b*N_ + i];
    int valid = (idv >= 0) ? 1 : 0;
    nums[i] = ni;
    if (i == 0) cnt = 0;
    __syncthreads();
    int p = 0;
    for (int j = 0; j < N_; ++j) {
        float nj = nums[j];
        p += (nj < ni || (nj == ni && j < i)) ? 1 : 0;   // total order, ties by index
    }
    sig[p] = i;
    atomicAdd(&cnt, valid);
    __syncthreads();
    sigma[b*N_ + i] = sig[i];
    int cur = sig[i];
    int prv = (i > 0) ? sig[i-1] : 0;
    newgrp[b*N_ + i] = (i == 0 || nums[cur] != nums[prv]) ? 1 : 0;
    respv[b*N_ + i] = ((is_resp[b*N_ + i] == 1) ? 1 : 0) | (valid << 1);
    if (i == 0) denom[b] = fmaxf((float)(cnt - 1), 1.0f);
}

// ---------------------------------------------------------------------------
// Kernel 0b: global class partition. Single block, 1024 threads, 2 rows each.
// perm: class-0 rows pack at [0,C0), class-1 at [P0, P0+C1), P0 = ceil128(C0).
__global__ void k_meta(const int* __restrict__ respv, int* __restrict__ aperm,
                       int* __restrict__ iperm, int* __restrict__ meta) {
    __shared__ int s0[1024], s1[1024];
    int t = threadIdx.x;
    aperm[t] = -1; aperm[t + 1024] = -1;
    if (t < MP - 2048) aperm[t + 2048] = -1;
    int r0 = 2*t, r1 = 2*t + 1;
    int c_a = respv[r0] & 1, c_b = respv[r1] & 1;
    int a0 = 1 - c_a, b0 = 1 - c_b;
    s0[t] = a0 + b0;
    s1[t] = c_a + c_b;
    __syncthreads();
    for (int off = 1; off < 1024; off <<= 1) {
        int v0 = (t >= off) ? s0[t-off] : 0;
        int v1 = (t >= off) ? s1[t-off] : 0;
        __syncthreads();
        s0[t] += v0; s1[t] += v1;
        __syncthreads();
    }
    int C0 = s0[1023], C1 = s1[1023];
    int P0 = ((C0 + 127) >> 7) << 7;
    int ex0 = s0[t] - (a0 + b0);     // exclusive prefix over pairs
    int ex1 = s1[t] - (c_a + c_b);
    int p_a = (c_a == 0) ? ex0 : P0 + ex1;
    int p_b = (c_b == 0) ? ex0 + a0 : P0 + ex1 + c_a;
    aperm[p_a] = r0; iperm[r0] = p_a;
    aperm[p_b] = r1; iperm[r1] = p_b;
    if (t == 0) { meta[0] = P0; meta[1] = C0; meta[2] = C1; }
}

// ---------------------------------------------------------------------------
// Kernel 1: gather Init, alpha = sigmoid(Init.w_alpha), Init -> A[pr] slot 4,
// ascaled = valid * alpha / denom.
__global__ void k_gather(const float* __restrict__ word_emb, const int* __restrict__ num_ids,
                         const float* __restrict__ w_alpha, const float* __restrict__ b_alpha,
                         const float* __restrict__ denom, const int* __restrict__ iperm,
                         bf16* __restrict__ A, float* __restrict__ ascaled) {
    int blk = blockIdx.x;
    int b = blk >> 7, n = blk & 127;
    int t = threadIdx.x;
    int idv = num_ids[b*N_ + n];
    int valid = (idv >= 0) ? 1 : 0;
    int idx = idv < 0 ? 0 : (idv > S_-1 ? S_-1 : idv);
    int pr = iperm[b*N_ + n];
    const float4* row = (const float4*)(word_emb + ((size_t)b*S_ + idx)*H_);
    float4 v = row[t];
    float4 w = ((const float4*)w_alpha)[t];
    float part = v.x*w.x + v.y*w.y + v.z*w.z + v.w*w.w;
    bf16* dst = A + (size_t)pr*K5 + 4*H_ + t*4;
    dst[0] = __float2bfloat16(v.x);
    dst[1] = __float2bfloat16(v.y);
    dst[2] = __float2bfloat16(v.z);
    dst[3] = __float2bfloat16(v.w);
#pragma unroll
    for (int off = 32; off > 0; off >>= 1) part += __shfl_down(part, off, 64);
    __shared__ float red[4];
    if ((t & 63) == 0) red[t >> 6] = part;
    __syncthreads();
    if (t == 0) {
        float dot = red[0] + red[1] + red[2] + red[3] + b_alpha[0];
        float al = 1.0f / (1.0f + __expf(-dot));
        ascaled[b*N_ + n] = valid ? (al / denom[b]) : 0.0f;
    }
}

// ---------------------------------------------------------------------------
// Kernel 2a: W_r -> Wt[class][slot 0..3]. r = 4*(s>>1) + 2*c + (s&1). 8192 blocks.
__global__ void k_wt(const float* __restrict__ W_r, bf16* __restrict__ Wt) {
    size_t o = ((size_t)blockIdx.x*256 + threadIdx.x)*4;   // over 2*4*H*H elems
    int cs = (int)(o >> 20);                               // H*H = 2^20
    int c = cs >> 2, s = cs & 3;
    int r = ((s >> 1) << 2) + 2*c + (s & 1);
    size_t off = o & (size_t)(H_*H_ - 1);
    float4 v = *(const float4*)(W_r + (size_t)r*H_*H_ + off);
    bf16* dst = Wt + (size_t)(c*5 + s)*H_*H_ + off;
    dst[0] = __float2bfloat16(v.x);
    dst[1] = __float2bfloat16(v.y);
    dst[2] = __float2bfloat16(v.z);
    dst[3] = __float2bfloat16(v.w);
}

// Kernel 2b: w_f [k][n] -> slot 4 as [n][k] in BOTH class stacks. LDS transpose.
__global__ void k_wf(const float* __restrict__ w_f, bf16* __restrict__ Wt) {
    __shared__ float lds[64][65];
    int bi = blockIdx.x, bj = blockIdx.y;
    int t = threadIdx.x;
    int ty = t >> 4, tx = t & 15;
#pragma unroll
    for (int i = 0; i < 4; ++i) {
        int r = ty*4 + i;                                    // k index within tile
        float4 v = *(const float4*)(w_f + (size_t)(bi*64 + r)*H_ + bj*64 + tx*4);
        lds[r][tx*4+0] = v.x; lds[r][tx*4+1] = v.y;
        lds[r][tx*4+2] = v.z; lds[r][tx*4+3] = v.w;
    }
    __syncthreads();
    bf16* d0 = Wt + (size_t)4*H_*H_;        // class 0 slot 4
    bf16* d1 = Wt + (size_t)9*H_*H_;        // class 1 slot 4
#pragma unroll
    for (int i = 0; i < 4; ++i) {
        int n = ty*4 + i;
        size_t doff = (size_t)(bj*64 + n)*H_ + bi*64 + tx*4;
#pragma unroll
        for (int j = 0; j < 4; ++j) {
            bf16 val = __float2bfloat16(lds[tx*4+j][n]);
            d0[doff + j] = val;
            d1[doff + j] = val;
        }
    }
}

// ---------------------------------------------------------------------------
// Kernel 2c: zero padding rows of A (aperm[pr] < 0). ws is poisoned 0xAA.
__global__ void k_pad(const int* __restrict__ aperm, bf16* __restrict__ A) {
    int pr = blockIdx.x;
    if (aperm[pr] >= 0) return;
    float4 z = {0.f, 0.f, 0.f, 0.f};
    float4* dst = (float4*)(A + (size_t)pr*K5);   // 5120 bf16 = 640 x 16B
    for (int c = threadIdx.x; c < 640; c += 256) dst[c] = z;
}

// ---------------------------------------------------------------------------
// Kernel 3: build A slots 0-3 via prefix sums over sorted order.
// Compact layout: s0=L0, s1=L1, s2=G0, s3=G1 (class picks the weight stack).
__global__ void k_build(const float* __restrict__ ascaled, const int* __restrict__ sigma,
                        const int* __restrict__ newgrp, const int* __restrict__ respv,
                        const int* __restrict__ iperm, bf16* __restrict__ A) {
    int b = blockIdx.y;
    int h = blockIdx.x*64 + threadIdx.x;
    __shared__ float as_s[N_];
    __shared__ int sig_s[N_], ng_s[N_], rv_s[N_], pm_s[N_];
    for (int j = threadIdx.x; j < N_; j += 64) {
        as_s[j] = ascaled[b*N_ + j];
        sig_s[j] = sigma[b*N_ + j];
        ng_s[j] = newgrp[b*N_ + j];
        rv_s[j] = respv[b*N_ + j];
        pm_s[j] = iperm[b*N_ + j];
    }
    __syncthreads();
    const bf16* initcol = A + 4*H_ + h;          // + pr*K5
    float tot0 = 0.f, tot1 = 0.f;
    for (int i2 = 0; i2 < N_; ++i2) {
        float v = as_s[i2] * __bfloat162float(initcol[(size_t)pm_s[i2]*K5]);
        if (rv_s[i2] & 1) tot1 += v; else tot0 += v;
    }
    float cS0=0.f, cS1=0.f, cG0=0.f, cG1=0.f;   // strict prefix + current tie group
    for (int p = 0; p < N_; ++p) {
        int i2 = sig_s[p];
        if (ng_s[p]) { cS0 += cG0; cS1 += cG1; cG0 = 0.f; cG1 = 0.f; }
        float v = as_s[i2] * __bfloat162float(initcol[(size_t)pm_s[i2]*K5]);
        int resp = rv_s[i2] & 1;
        float vf = (rv_s[i2] >> 1) ? 1.0f : 0.0f;
        float G0 = cS0, G1 = cS1;                    // senders with num_j < num_i
        float L0 = tot0 - G0 - (resp ? 0.f : v);     // num_j >= num_i, j != i
        float L1 = tot1 - G1 - (resp ? v : 0.f);
        bf16* Ar = A + (size_t)pm_s[i2]*K5 + h;
        Ar[0*H_] = __float2bfloat16(L0*vf);
        Ar[1*H_] = __float2bfloat16(L1*vf);
        Ar[2*H_] = __float2bfloat16(G0*vf);
        Ar[3*H_] = __float2bfloat16(G1*vf);
        if (resp) cG1 += v; else cG0 += v;
    }
}

// ---------------------------------------------------------------------------
// Kernel 4: split-K GEMM  acc[2176,1024] += A[2176,5120] x Wt_class^T (atomicAdd).
// BM=BN=128, BK=32, KSPLIT=8 -> grid 17 x 8 x 8 = 1088 blocks (~4/CU).
// LDS chunk layout [kchunk][row]: conflict-free (verified 0 conflicts R2/R3).
#define BM 128
#define BN 128
#define BK 32
#define KSEG 640     // K5/8 = 20 iters of BK

__global__ __launch_bounds__(256) void k_gemm(const bf16* __restrict__ A,
                                              const bf16* __restrict__ Wt,
                                              const int* __restrict__ meta,
                                              float* __restrict__ acc_buf) {
    __shared__ __align__(16) bf16 As[BM*BK];   // 8 KB
    __shared__ __align__(16) bf16 Bs[BN*BK];   // 8 KB
    int tid = threadIdx.x;
    int w = tid >> 6, lane = tid & 63;
    int q = lane >> 4, r = lane & 15;
    int bid = blockIdx.x;
    int mt = bid % 17;
    int rest = bid / 17;
    int nt = rest & 7, ks = rest >> 3;
    int rowBase = mt * BM, colBase = nt * BN;
    int wm = w >> 1, wn = w & 1;
    int P0 = meta[0];
    const bf16* Wtc = Wt + ((rowBase >= P0) ? (size_t)5*H_*H_ : 0);

    f4vec acc[4][4];
#pragma unroll
    for (int mi = 0; mi < 4; ++mi)
#pragma unroll
        for (int ni = 0; ni < 4; ++ni)
#pragma unroll
            for (int e = 0; e < 4; ++e) acc[mi][ni][e] = 0.0f;

    const size_t Abase = (size_t)rowBase * K5;
    const int kbeg = ks * KSEG, kend = kbeg + KSEG;
    for (int k0 = kbeg; k0 < kend; k0 += BK) {
        int slot = k0 >> 10, kin = k0 & 1023;
        {
            int c = tid;   // A: 512 chunks, 2/thread; kq=c>>7, row=c&127
            const bf16* g = A + Abase + (size_t)(c & 127)*K5 + k0 + (c >> 7)*8;
            __builtin_amdgcn_global_load_lds((const __attribute__((address_space(1))) void*)g,
                (__attribute__((address_space(3))) void*)((char*)As + w*1024), 16, 0, 0);
            c = tid + 256;
            const bf16* g2 = A + Abase + (size_t)(c & 127)*K5 + k0 + (c >> 7)*8;
            __builtin_amdgcn_global_load_lds((const __attribute__((address_space(1))) void*)g2,
                (__attribute__((address_space(3))) void*)((char*)As + 4096 + w*1024), 16, 0, 0);
            c = tid;       // B: 512 chunks, 2/thread
            const bf16* gb = Wtc + (size_t)slot*H_*H_ + (size_t)(colBase + (c & 127))*H_
                             + kin + (c >> 7)*8;
            __builtin_amdgcn_global_load_lds((const __attribute__((address_space(1))) void*)gb,
                (__attribute__((address_space(3))) void*)((char*)Bs + w*1024), 16, 0, 0);
            c = tid + 256;
            const bf16* gb2 = Wtc + (size_t)slot*H_*H_ + (size_t)(colBase + (c & 127))*H_
                              + kin + (c >> 7)*8;
            __builtin_amdgcn_global_load_lds((const __attribute__((address_space(1))) void*)gb2,
                (__attribute__((address_space(3))) void*)((char*)Bs + 4096 + w*1024), 16, 0, 0);
        }
        __syncthreads();
        const short* Asp = (const short*)As;
        const short* Bsp = (const short*)Bs;
        s8vec af[4], bfr[4];
#pragma unroll
        for (int mi = 0; mi < 4; ++mi)
            af[mi] = *(const s8vec*)(Asp + ((size_t)q*128 + wm*64 + mi*16 + r)*8);
#pragma unroll
        for (int ni = 0; ni < 4; ++ni)
            bfr[ni] = *(const s8vec*)(Bsp + ((size_t)q*128 + wn*64 + ni*16 + r)*8);
#pragma unroll
        for (int mi = 0; mi < 4; ++mi)
#pragma unroll
            for (int ni = 0; ni < 4; ++ni)
                acc[mi][ni] = __builtin_amdgcn_mfma_f32_16x16x32_bf16(af[mi], bfr[ni],
                                                                      acc[mi][ni], 0, 0, 0);
        __syncthreads();
    }

#pragma unroll
    for (int mi = 0; mi < 4; ++mi)
#pragma unroll
        for (int ni = 0; ni < 4; ++ni)
#pragma unroll
            for (int e = 0; e < 4; ++e) {
                int rr = rowBase + wm*64 + mi*16 + q*4 + e;   // D row = quad*4+reg
                int cc = colBase + wn*64 + ni*16 + r;         // D col = lane&15
                atomicAdd(&acc_buf[(size_t)rr*H_ + cc], acc[mi][ni][e]);
            }
}

// ---------------------------------------------------------------------------
// Kernel 5: epilogue out[row] = relu(acc_buf[iperm[row]] + b_f). 2048 blocks x 256.
__global__ void k_epi(const float* __restrict__ acc_buf, const int* __restrict__ iperm,
                      const float* __restrict__ b_f, float* __restrict__ out) {
    int row = blockIdx.x;
    int pr = iperm[row];
    int t = threadIdx.x;
    float4 v = ((const float4*)(acc_buf + (size_t)pr*H_))[t];
    float4 bv = ((const float4*)b_f)[t];
    v.x = fmaxf(v.x + bv.x, 0.0f);
    v.y = fmaxf(v.y + bv.y, 0.0f);
    v.z = fmaxf(v.z + bv.z, 0.0f);
    v.w = fmaxf(v.w + bv.w, 0.0f);
    ((float4*)(out + (size_t)row*H_))[t] = v;
}

// ---------------------------------------------------------------------------
extern "C" void kernel_launch(void* const* d_in, const int* in_sizes, int n_in,
                              void* d_out, int out_size, void* d_ws, size_t ws_size,
                              hipStream_t stream) {
    (void)in_sizes; (void)n_in; (void)out_size; (void)ws_size;
    const float* word_emb = (const float*)d_in[0];
    const int*   num_ids  = (const int*)d_in[1];
    const int*   is_resp  = (const int*)d_in[2];
    const float* numbers  = (const float*)d_in[3];
    const float* w_alpha  = (const float*)d_in[4];
    const float* b_alpha  = (const float*)d_in[5];
    const float* w_f      = (const float*)d_in[6];
    const float* b_f      = (const float*)d_in[7];
    const float* W_r      = (const float*)d_in[8];
    float* out = (float*)d_out;

    char* ws = (char*)d_ws;
    bf16*  Aws     = (bf16*)(ws);                    // [2176][5120] = 22,282,240 B
    bf16*  Wt      = (bf16*)(ws + 22282240);         // [2][5][1024][1024] = 20,971,520 B
    float* acc_buf = (float*)(ws + 43253760);        // [2176][1024] f32 = 8,912,896 B
    float* ascaled = (float*)(ws + 52166656);
    int*   sigma   = (int*)(ws + 52174848);
    int*   newgrp  = (int*)(ws + 52183040);
    int*   respv   = (int*)(ws + 52191232);
    float* denom   = (float*)(ws + 52199424);
    int*   aperm   = (int*)(ws + 52199488);          // [2176]
    int*   iperm   = (int*)(ws + 52208192);          // [2048]
    int*   meta    = (int*)(ws + 52216384);          // [4]

    hipMemsetAsync(acc_buf, 0, (size_t)MP*H_*sizeof(float), stream);
    k_sort  <<<16,   128, 0, stream>>>(num_ids, is_resp, numbers, sigma, newgrp, respv, denom);
    k_meta  <<<1,   1024, 0, stream>>>(respv, aperm, iperm, meta);
    k_gather<<<2048, 256, 0, stream>>>(word_emb, num_ids, w_alpha, b_alpha, denom, iperm,
                                       Aws, ascaled);
    k_wt    <<<8192, 256, 0, stream>>>(W_r, Wt);
    k_wf    <<<dim3(16,16), 256, 0, stream>>>(w_f, Wt);
    k_pad   <<<MP,   256, 0, stream>>>(aperm, Aws);
    k_build <<<dim3(16,16), 64, 0, stream>>>(ascaled, sigma, newgrp, respv, iperm, Aws);
    k_gemm  <<<1088, 256, 0, stream>>>(Aws, Wt, meta, acc_buf);
    k_epi   <<<2048, 256, 0, stream>>>(acc_buf, iperm, b_f, out);
}

// Round 5
// 349.461 us; speedup vs baseline: 1.1433x; 1.0585x over previous
//
#include <hip/hip_runtime.h>
#include <hip/hip_bf16.h>
#include <stdint.h>

#define B_ 16
#define S_ 2048
#define H_ 1024
#define N_ 128
#define M_ (B_*N_)    // 2048
#define K5 5120       // compact: 4 relation slots + Init slot (slot 4)
#define MP 2176       // padded rows: 17 tiles of 128 (class-0 block | class-1 block | pad)

typedef __attribute__((ext_vector_type(8))) short s8vec;   // 8 x bf16 (4 VGPRs)
typedef __attribute__((ext_vector_type(4))) float f4vec;
typedef __hip_bfloat16 bf16;

// ---------------------------------------------------------------------------
// Kernel 0: per-batch sort by `numbers`, validity count, tie-group flags.
__global__ void k_sort(const int* __restrict__ num_ids, const int* __restrict__ is_resp,
                       const float* __restrict__ numbers,
                       int* __restrict__ sigma, int* __restrict__ newgrp,
                       int* __restrict__ respv, float* __restrict__ denom) {
    int b = blockIdx.x, i = threadIdx.x;
    __shared__ float nums[N_];
    __shared__ int sig[N_];
    __shared__ int cnt;
    float ni = numbers[b*N_ + i];
    int idv = num_ids[b*N_ + i];
    int valid = (idv >= 0) ? 1 : 0;
    nums[i] = ni;
    if (i == 0) cnt = 0;
    __syncthreads();
    int p = 0;
    for (int j = 0; j < N_; ++j) {
        float nj = nums[j];
        p += (nj < ni || (nj == ni && j < i)) ? 1 : 0;   // total order, ties by index
    }
    sig[p] = i;
    atomicAdd(&cnt, valid);
    __syncthreads();
    sigma[b*N_ + i] = sig[i];
    int cur = sig[i];
    int prv = (i > 0) ? sig[i-1] : 0;
    newgrp[b*N_ + i] = (i == 0 || nums[cur] != nums[prv]) ? 1 : 0;
    respv[b*N_ + i] = ((is_resp[b*N_ + i] == 1) ? 1 : 0) | (valid << 1);
    if (i == 0) denom[b] = fmaxf((float)(cnt - 1), 1.0f);
}

// ---------------------------------------------------------------------------
// Kernel 0b: global class partition. Single block, 1024 threads, 2 rows each.
// perm: class-0 rows pack at [0,C0), class-1 at [P0, P0+C1), P0 = ceil128(C0).
__global__ void k_meta(const int* __restrict__ respv, int* __restrict__ aperm,
                       int* __restrict__ iperm, int* __restrict__ meta) {
    __shared__ int s0[1024], s1[1024];
    int t = threadIdx.x;
    aperm[t] = -1; aperm[t + 1024] = -1;
    if (t < MP - 2048) aperm[t + 2048] = -1;
    int r0 = 2*t, r1 = 2*t + 1;
    int c_a = respv[r0] & 1, c_b = respv[r1] & 1;
    int a0 = 1 - c_a, b0 = 1 - c_b;
    s0[t] = a0 + b0;
    s1[t] = c_a + c_b;
    __syncthreads();
    for (int off = 1; off < 1024; off <<= 1) {
        int v0 = (t >= off) ? s0[t-off] : 0;
        int v1 = (t >= off) ? s1[t-off] : 0;
        __syncthreads();
        s0[t] += v0; s1[t] += v1;
        __syncthreads();
    }
    int C0 = s0[1023], C1 = s1[1023];
    int P0 = ((C0 + 127) >> 7) << 7;
    int ex0 = s0[t] - (a0 + b0);     // exclusive prefix over pairs
    int ex1 = s1[t] - (c_a + c_b);
    int p_a = (c_a == 0) ? ex0 : P0 + ex1;
    int p_b = (c_b == 0) ? ex0 + a0 : P0 + ex1 + c_a;
    aperm[p_a] = r0; iperm[r0] = p_a;
    aperm[p_b] = r1; iperm[r1] = p_b;
    if (t == 0) { meta[0] = P0; meta[1] = C0; meta[2] = C1; }
}

// ---------------------------------------------------------------------------
// Kernel 1: gather Init, alpha = sigmoid(Init.w_alpha), Init -> A[pr] slot 4,
// ascaled = valid * alpha / denom.
__global__ void k_gather(const float* __restrict__ word_emb, const int* __restrict__ num_ids,
                         const float* __restrict__ w_alpha, const float* __restrict__ b_alpha,
                         const float* __restrict__ denom, const int* __restrict__ iperm,
                         bf16* __restrict__ A, float* __restrict__ ascaled) {
    int blk = blockIdx.x;
    int b = blk >> 7, n = blk & 127;
    int t = threadIdx.x;
    int idv = num_ids[b*N_ + n];
    int valid = (idv >= 0) ? 1 : 0;
    int idx = idv < 0 ? 0 : (idv > S_-1 ? S_-1 : idv);
    int pr = iperm[b*N_ + n];
    const float4* row = (const float4*)(word_emb + ((size_t)b*S_ + idx)*H_);
    float4 v = row[t];
    float4 w = ((const float4*)w_alpha)[t];
    float part = v.x*w.x + v.y*w.y + v.z*w.z + v.w*w.w;
    bf16* dst = A + (size_t)pr*K5 + 4*H_ + t*4;
    dst[0] = __float2bfloat16(v.x);
    dst[1] = __float2bfloat16(v.y);
    dst[2] = __float2bfloat16(v.z);
    dst[3] = __float2bfloat16(v.w);
#pragma unroll
    for (int off = 32; off > 0; off >>= 1) part += __shfl_down(part, off, 64);
    __shared__ float red[4];
    if ((t & 63) == 0) red[t >> 6] = part;
    __syncthreads();
    if (t == 0) {
        float dot = red[0] + red[1] + red[2] + red[3] + b_alpha[0];
        float al = 1.0f / (1.0f + __expf(-dot));
        ascaled[b*N_ + n] = valid ? (al / denom[b]) : 0.0f;
    }
}

// ---------------------------------------------------------------------------
// Kernel 2a: W_r -> Wt[class][slot 0..3]. r = 4*(s>>1) + 2*c + (s&1). 8192 blocks.
__global__ void k_wt(const float* __restrict__ W_r, bf16* __restrict__ Wt) {
    size_t o = ((size_t)blockIdx.x*256 + threadIdx.x)*4;   // over 2*4*H*H elems
    int cs = (int)(o >> 20);                               // H*H = 2^20
    int c = cs >> 2, s = cs & 3;
    int r = ((s >> 1) << 2) + 2*c + (s & 1);
    size_t off = o & (size_t)(H_*H_ - 1);
    float4 v = *(const float4*)(W_r + (size_t)r*H_*H_ + off);
    bf16* dst = Wt + (size_t)(c*5 + s)*H_*H_ + off;
    dst[0] = __float2bfloat16(v.x);
    dst[1] = __float2bfloat16(v.y);
    dst[2] = __float2bfloat16(v.z);
    dst[3] = __float2bfloat16(v.w);
}

// Kernel 2b: w_f [k][n] -> slot 4 as [n][k] in BOTH class stacks. LDS transpose.
__global__ void k_wf(const float* __restrict__ w_f, bf16* __restrict__ Wt) {
    __shared__ float lds[64][65];
    int bi = blockIdx.x, bj = blockIdx.y;
    int t = threadIdx.x;
    int ty = t >> 4, tx = t & 15;
#pragma unroll
    for (int i = 0; i < 4; ++i) {
        int r = ty*4 + i;                                    // k index within tile
        float4 v = *(const float4*)(w_f + (size_t)(bi*64 + r)*H_ + bj*64 + tx*4);
        lds[r][tx*4+0] = v.x; lds[r][tx*4+1] = v.y;
        lds[r][tx*4+2] = v.z; lds[r][tx*4+3] = v.w;
    }
    __syncthreads();
    bf16* d0 = Wt + (size_t)4*H_*H_;        // class 0 slot 4
    bf16* d1 = Wt + (size_t)9*H_*H_;        // class 1 slot 4
#pragma unroll
    for (int i = 0; i < 4; ++i) {
        int n = ty*4 + i;
        size_t doff = (size_t)(bj*64 + n)*H_ + bi*64 + tx*4;
#pragma unroll
        for (int j = 0; j < 4; ++j) {
            bf16 val = __float2bfloat16(lds[tx*4+j][n]);
            d0[doff + j] = val;
            d1[doff + j] = val;
        }
    }
}

// ---------------------------------------------------------------------------
// Kernel 2c: zero padding rows of A (aperm[pr] < 0). ws is poisoned 0xAA.
__global__ void k_pad(const int* __restrict__ aperm, bf16* __restrict__ A) {
    int pr = blockIdx.x;
    if (aperm[pr] >= 0) return;
    float4 z = {0.f, 0.f, 0.f, 0.f};
    float4* dst = (float4*)(A + (size_t)pr*K5);   // 5120 bf16 = 640 x 16B
    for (int c = threadIdx.x; c < 640; c += 256) dst[c] = z;
}

// ---------------------------------------------------------------------------
// Kernel 3: build A slots 0-3 via prefix sums over sorted order.
// Compact layout: s0=L0, s1=L1, s2=G0, s3=G1 (class picks the weight stack).
__global__ void k_build(const float* __restrict__ ascaled, const int* __restrict__ sigma,
                        const int* __restrict__ newgrp, const int* __restrict__ respv,
                        const int* __restrict__ iperm, bf16* __restrict__ A) {
    int b = blockIdx.y;
    int h = blockIdx.x*64 + threadIdx.x;
    __shared__ float as_s[N_];
    __shared__ int sig_s[N_], ng_s[N_], rv_s[N_], pm_s[N_];
    for (int j = threadIdx.x; j < N_; j += 64) {
        as_s[j] = ascaled[b*N_ + j];
        sig_s[j] = sigma[b*N_ + j];
        ng_s[j] = newgrp[b*N_ + j];
        rv_s[j] = respv[b*N_ + j];
        pm_s[j] = iperm[b*N_ + j];
    }
    __syncthreads();
    const bf16* initcol = A + 4*H_ + h;          // + pr*K5
    float tot0 = 0.f, tot1 = 0.f;
    for (int i2 = 0; i2 < N_; ++i2) {
        float v = as_s[i2] * __bfloat162float(initcol[(size_t)pm_s[i2]*K5]);
        if (rv_s[i2] & 1) tot1 += v; else tot0 += v;
    }
    float cS0=0.f, cS1=0.f, cG0=0.f, cG1=0.f;   // strict prefix + current tie group
    for (int p = 0; p < N_; ++p) {
        int i2 = sig_s[p];
        if (ng_s[p]) { cS0 += cG0; cS1 += cG1; cG0 = 0.f; cG1 = 0.f; }
        float v = as_s[i2] * __bfloat162float(initcol[(size_t)pm_s[i2]*K5]);
        int resp = rv_s[i2] & 1;
        float vf = (rv_s[i2] >> 1) ? 1.0f : 0.0f;
        float G0 = cS0, G1 = cS1;                    // senders with num_j < num_i
        float L0 = tot0 - G0 - (resp ? 0.f : v);     // num_j >= num_i, j != i
        float L1 = tot1 - G1 - (resp ? v : 0.f);
        bf16* Ar = A + (size_t)pm_s[i2]*K5 + h;
        Ar[0*H_] = __float2bfloat16(L0*vf);
        Ar[1*H_] = __float2bfloat16(L1*vf);
        Ar[2*H_] = __float2bfloat16(G0*vf);
        Ar[3*H_] = __float2bfloat16(G1*vf);
        if (resp) cG1 += v; else cG0 += v;
    }
}

// ---------------------------------------------------------------------------
// Kernel 4: split-K GEMM  acc[2176,1024] += A[2176,5120] x Wt_class^T (atomicAdd).
// BM=BN=128, BK=32, KSPLIT=5 (one weight matrix per split) -> 17 x 8 x 5 = 680
// blocks (~2.7/CU). Staging: m97-style row-contiguous global chunks (4 lanes =
// 64B of one row) with XOR piece swizzle p = (c&3)^((c>>4)&3) so that
// ds_read_b128 bank-quads tile 32 banks exactly 2x (free 2-way). ks is the
// slowest bid digit -> atomic writers of a region are temporally separated.
#define BM 128
#define BN 128
#define BK 32

__global__ __launch_bounds__(256) void k_gemm(const bf16* __restrict__ A,
                                              const bf16* __restrict__ Wt,
                                              const int* __restrict__ meta,
                                              float* __restrict__ acc_buf) {
    __shared__ __align__(16) bf16 As[BM*BK];   // 8 KB; chunk c -> row c>>2, piece (c&3)^((c>>4)&3)
    __shared__ __align__(16) bf16 Bs[BN*BK];   // 8 KB, same scheme over out-cols
    int tid = threadIdx.x;
    int w = tid >> 6, lane = tid & 63;
    int q = lane >> 4, r = lane & 15;
    int bid = blockIdx.x;
    int mt = bid % 17;
    int rest = bid / 17;
    int nt = rest & 7, ks = rest >> 3;        // ks slowest
    int rowBase = mt * BM, colBase = nt * BN;
    int wm = w >> 1, wn = w & 1;
    int P0 = meta[0];
    const bf16* Wtc = Wt + ((rowBase >= P0) ? (size_t)5*H_*H_ : 0) + (size_t)ks*H_*H_;

    f4vec acc[4][4];
#pragma unroll
    for (int mi = 0; mi < 4; ++mi)
#pragma unroll
        for (int ni = 0; ni < 4; ++ni)
#pragma unroll
            for (int e = 0; e < 4; ++e) acc[mi][ni][e] = 0.0f;

    const size_t Abase = (size_t)rowBase * K5 + (size_t)ks * H_;   // k offset = ks*1024
    const int swz = q ^ ((r >> 2) & 3);       // ds_read piece-slot swizzle (per lane)

    for (int kin = 0; kin < 1024; kin += BK) {
        // ---- stage A: 512 chunks (2/thread). chunk c: row=c>>2, slot=c&3,
        // global piece p = (c&3)^((c>>4)&3). 4-lane groups read 64B contiguous.
        {
            int c = tid;
            int p = (c & 3) ^ ((c >> 4) & 3);
            const bf16* g = A + Abase + (size_t)(c >> 2)*K5 + kin + p*8;
            __builtin_amdgcn_global_load_lds((const __attribute__((address_space(1))) void*)g,
                (__attribute__((address_space(3))) void*)((char*)As + w*1024), 16, 0, 0);
            c = tid + 256;
            p = (c & 3) ^ ((c >> 4) & 3);
            const bf16* g2 = A + Abase + (size_t)(c >> 2)*K5 + kin + p*8;
            __builtin_amdgcn_global_load_lds((const __attribute__((address_space(1))) void*)g2,
                (__attribute__((address_space(3))) void*)((char*)As + 4096 + w*1024), 16, 0, 0);
            // ---- stage B: 512 chunks (2/thread), cols of Wtc
            c = tid;
            p = (c & 3) ^ ((c >> 4) & 3);
            const bf16* gb = Wtc + (size_t)(colBase + (c >> 2))*H_ + kin + p*8;
            __builtin_amdgcn_global_load_lds((const __attribute__((address_space(1))) void*)gb,
                (__attribute__((address_space(3))) void*)((char*)Bs + w*1024), 16, 0, 0);
            c = tid + 256;
            p = (c & 3) ^ ((c >> 4) & 3);
            const bf16* gb2 = Wtc + (size_t)(colBase + (c >> 2))*H_ + kin + p*8;
            __builtin_amdgcn_global_load_lds((const __attribute__((address_space(1))) void*)gb2,
                (__attribute__((address_space(3))) void*)((char*)Bs + 4096 + w*1024), 16, 0, 0);
        }
        __syncthreads();
        const short* Asp = (const short*)As;
        const short* Bsp = (const short*)Bs;
        s8vec af[4], bfr[4];
#pragma unroll
        for (int mi = 0; mi < 4; ++mi) {
            int R = wm*64 + mi*16 + r;
            af[mi] = *(const s8vec*)(Asp + R*32 + (swz << 3));
        }
#pragma unroll
        for (int ni = 0; ni < 4; ++ni) {
            int C = wn*64 + ni*16 + r;
            bfr[ni] = *(const s8vec*)(Bsp + C*32 + (swz << 3));
        }
#pragma unroll
        for (int mi = 0; mi < 4; ++mi)
#pragma unroll
            for (int ni = 0; ni < 4; ++ni)
                acc[mi][ni] = __builtin_amdgcn_mfma_f32_16x16x32_bf16(af[mi], bfr[ni],
                                                                      acc[mi][ni], 0, 0, 0);
        __syncthreads();
    }

#pragma unroll
    for (int mi = 0; mi < 4; ++mi)
#pragma unroll
        for (int ni = 0; ni < 4; ++ni)
#pragma unroll
            for (int e = 0; e < 4; ++e) {
                int rr = rowBase + wm*64 + mi*16 + q*4 + e;   // D row = quad*4+reg
                int cc = colBase + wn*64 + ni*16 + r;         // D col = lane&15
                atomicAdd(&acc_buf[(size_t)rr*H_ + cc], acc[mi][ni][e]);
            }
}

// ---------------------------------------------------------------------------
// Kernel 5: epilogue out[row] = relu(acc_buf[iperm[row]] + b_f). 2048 blocks x 256.
__global__ void k_epi(const float* __restrict__ acc_buf, const int* __restrict__ iperm,
                      const float* __restrict__ b_f, float* __restrict__ out) {
    int row = blockIdx.x;
    int pr = iperm[row];
    int t = threadIdx.x;
    float4 v = ((const float4*)(acc_buf + (size_t)pr*H_))[t];
    float4 bv = ((const float4*)b_f)[t];
    v.x = fmaxf(v.x + bv.x, 0.0f);
    v.y = fmaxf(v.y + bv.y, 0.0f);
    v.z = fmaxf(v.z + bv.z, 0.0f);
    v.w = fmaxf(v.w + bv.w, 0.0f);
    ((float4*)(out + (size_t)row*H_))[t] = v;
}

// ---------------------------------------------------------------------------
extern "C" void kernel_launch(void* const* d_in, const int* in_sizes, int n_in,
                              void* d_out, int out_size, void* d_ws, size_t ws_size,
                              hipStream_t stream) {
    (void)in_sizes; (void)n_in; (void)out_size; (void)ws_size;
    const float* word_emb = (const float*)d_in[0];
    const int*   num_ids  = (const int*)d_in[1];
    const int*   is_resp  = (const int*)d_in[2];
    const float* numbers  = (const float*)d_in[3];
    const float* w_alpha  = (const float*)d_in[4];
    const float* b_alpha  = (const float*)d_in[5];
    const float* w_f      = (const float*)d_in[6];
    const float* b_f      = (const float*)d_in[7];
    const float* W_r      = (const float*)d_in[8];
    float* out = (float*)d_out;

    char* ws = (char*)d_ws;
    bf16*  Aws     = (bf16*)(ws);                    // [2176][5120] = 22,282,240 B
    bf16*  Wt      = (bf16*)(ws + 22282240);         // [2][5][1024][1024] = 20,971,520 B
    float* acc_buf = (float*)(ws + 43253760);        // [2176][1024] f32 = 8,912,896 B
    float* ascaled = (float*)(ws + 52166656);
    int*   sigma   = (int*)(ws + 52174848);
    int*   newgrp  = (int*)(ws + 52183040);
    int*   respv   = (int*)(ws + 52191232);
    float* denom   = (float*)(ws + 52199424);
    int*   aperm   = (int*)(ws + 52199488);          // [2176]
    int*   iperm   = (int*)(ws + 52208192);          // [2048]
    int*   meta    = (int*)(ws + 52216384);          // [4]

    hipMemsetAsync(acc_buf, 0, (size_t)MP*H_*sizeof(float), stream);
    k_sort  <<<16,   128, 0, stream>>>(num_ids, is_resp, numbers, sigma, newgrp, respv, denom);
    k_meta  <<<1,   1024, 0, stream>>>(respv, aperm, iperm, meta);
    k_gather<<<2048, 256, 0, stream>>>(word_emb, num_ids, w_alpha, b_alpha, denom, iperm,
                                       Aws, ascaled);
    k_wt    <<<8192, 256, 0, stream>>>(W_r, Wt);
    k_wf    <<<dim3(16,16), 256, 0, stream>>>(w_f, Wt);
    k_pad   <<<MP,   256, 0, stream>>>(aperm, Aws);
    k_build <<<dim3(16,16), 64, 0, stream>>>(ascaled, sigma, newgrp, respv, iperm, Aws);
    k_gemm  <<<680,  256, 0, stream>>>(Aws, Wt, meta, acc_buf);
    k_epi   <<<2048, 256, 0, stream>>>(acc_buf, iperm, b_f, out);
}